// Round 1
// baseline (51.497 us; speedup 1.0000x reference)
//
#include <hip/hip_runtime.h>

// B=8, N=128, COOR=3, F=128, FILT=128
#define BB   8
#define NN   128
#define FF   128
#define KK   128

// ---------------------------------------------------------------------------
// Kernel 1: precompute AC[b][n][c][k2], k2 in [0,256):
//   k2 <  128: A[b,n,c,k] = sum_f vf[b,n,c,f] * w_vs[f,    k]
//   k2 >= 128: C[b,n,c,k] = sum_f vf[b,n,c,f] * w_vs[128+f,k]
// One block handles 4 (b,n) rows; thread t owns one output column (half,col).
// vf reads are wave-uniform (scalarize to s_load); w reads are coalesced.
// ---------------------------------------------------------------------------
__global__ __launch_bounds__(256) void k_pre(const float* __restrict__ vf,
                                             const float* __restrict__ w,
                                             float* __restrict__ ac) {
    const int bn0  = blockIdx.x * 4;          // 256 blocks -> 1024 (b,n) rows
    const int tid  = threadIdx.x;
    const int col  = tid & 127;
    const int half = tid >> 7;                // 0 = A-half, 1 = C-half
    const float* wcol = w + half * (FF * KK) + col;   // read wcol[f*KK]
    const float* vrow = vf + (size_t)bn0 * (3 * FF);  // 4 rows x 384 floats

    float acc[4][3];
#pragma unroll
    for (int q = 0; q < 4; ++q)
#pragma unroll
        for (int c = 0; c < 3; ++c) acc[q][c] = 0.f;

#pragma unroll 4
    for (int f = 0; f < FF; ++f) {
        const float wv = wcol[f * KK];
#pragma unroll
        for (int q = 0; q < 4; ++q) {
#pragma unroll
            for (int c = 0; c < 3; ++c) {
                acc[q][c] = fmaf(wv, vrow[q * 384 + c * FF + f], acc[q][c]);
            }
        }
    }

#pragma unroll
    for (int q = 0; q < 4; ++q)
#pragma unroll
        for (int c = 0; c < 3; ++c)
            ac[((size_t)(bn0 + q) * 3 + c) * 256 + half * 128 + col] = acc[q][c];
}

// ---------------------------------------------------------------------------
// Kernel 2: out[b,i,j,k] = d0*(A0+C0) + d1*(A1+C1) + d2*(A2+C2) + (d0+d1+d2)*bias
// Grid: 8 * 32(i-tiles of 4) * 4(j-tiles of 32) = 1024 blocks, 256 threads.
// Thread: k4 = tid&31 (float4 of k), rg = tid>>5; i is CONSTANT per thread
// (ti = rg&3), so the A row + bias sit in registers for the whole block.
// j walks 2 rows per pass (rg4 = rg>>2 picks which), C rows get 4-way L1 reuse.
// Pure streaming: 64 MB coalesced float4 stores -> HBM-write-bound.
// ---------------------------------------------------------------------------
__global__ __launch_bounds__(256) void k_main(const float* __restrict__ dist,
                                              const float* __restrict__ ac,
                                              const float* __restrict__ bias,
                                              float* __restrict__ out) {
    const int bx  = blockIdx.x;
    const int b   = bx >> 7;            // 128 blocks per batch
    const int rem = bx & 127;
    const int it  = rem >> 2;           // 0..31
    const int jt  = rem & 3;            // 0..3
    const int i0  = it * 4, j0 = jt * 32;

    const int tid = threadIdx.x;
    const int k4  = tid & 31;           // float4 index within the 128 filters
    const int rg  = tid >> 5;           // 0..7
    const int ti  = rg & 3;
    const int rg4 = rg >> 2;            // 0..1
    const int i   = i0 + ti;

    const float4 bk = *(const float4*)(bias + k4 * 4);
    const float4* arow = (const float4*)(ac + (size_t)((b * NN + i) * 3) * 256) + k4;
    const float4 a0 = arow[0], a1 = arow[64], a2 = arow[128];

    const float* dbase = dist + (size_t)(b * NN + i) * NN * 3;
    float* obase = out + (size_t)(b * NN + i) * NN * KK;

#pragma unroll 4
    for (int p = 0; p < 16; ++p) {
        const int j = j0 + 2 * p + rg4;
        const float* dj = dbase + (size_t)j * 3;
        const float d0 = dj[0], d1 = dj[1], d2 = dj[2];
        const float sd = d0 + d1 + d2;

        const float4* crow = (const float4*)(ac + (size_t)((b * NN + j) * 3) * 256)
                             + 32 + k4;  // +128 floats: C-half
        const float4 c0 = crow[0], c1 = crow[64], c2 = crow[128];

        float4 r;
        r.x = fmaf(d0, a0.x + c0.x, fmaf(d1, a1.x + c1.x, fmaf(d2, a2.x + c2.x, sd * bk.x)));
        r.y = fmaf(d0, a0.y + c0.y, fmaf(d1, a1.y + c1.y, fmaf(d2, a2.y + c2.y, sd * bk.y)));
        r.z = fmaf(d0, a0.z + c0.z, fmaf(d1, a1.z + c1.z, fmaf(d2, a2.z + c2.z, sd * bk.z)));
        r.w = fmaf(d0, a0.w + c0.w, fmaf(d1, a1.w + c1.w, fmaf(d2, a2.w + c2.w, sd * bk.w)));

        *(float4*)(obase + (size_t)j * KK + k4 * 4) = r;
    }
}

// ---------------------------------------------------------------------------
// Fallback (only if ws_size < 3 MB): fused, recomputes C per j. Slow but correct.
// ---------------------------------------------------------------------------
__global__ __launch_bounds__(256) void k_fused_slow(const float* __restrict__ vf,
                                                    const float* __restrict__ dist,
                                                    const float* __restrict__ w,
                                                    const float* __restrict__ bias,
                                                    float* __restrict__ out) {
    const int bi  = blockIdx.x;           // b*NN + i
    const int b   = bi >> 7;
    const int tid = threadIdx.x;
    __shared__ float arow[384];
    __shared__ float crow[384];

    for (int idx = tid; idx < 384; idx += 256) {
        const int c = idx >> 7, k = idx & 127;
        const float* v = vf + (size_t)bi * 384 + c * 128;
        float s = 0.f;
        for (int f = 0; f < 128; ++f) s = fmaf(v[f], w[f * 128 + k], s);
        arow[idx] = s;
    }
    __syncthreads();

    for (int j = 0; j < NN; ++j) {
        for (int idx = tid; idx < 384; idx += 256) {
            const int c = idx >> 7, k = idx & 127;
            const float* v = vf + (size_t)(b * NN + j) * 384 + c * 128;
            float s = 0.f;
            for (int f = 0; f < 128; ++f) s = fmaf(v[f], w[(128 + f) * 128 + k], s);
            crow[idx] = s;
        }
        __syncthreads();
        if (tid < 128) {
            const float* dj = dist + ((size_t)bi * NN + j) * 3;
            const float d0 = dj[0], d1 = dj[1], d2 = dj[2];
            const float sd = d0 + d1 + d2;
            const float r = fmaf(d0, arow[tid] + crow[tid],
                            fmaf(d1, arow[128 + tid] + crow[128 + tid],
                            fmaf(d2, arow[256 + tid] + crow[256 + tid], sd * bias[tid])));
            out[((size_t)bi * NN + j) * 128 + tid] = r;
        }
        __syncthreads();
    }
}

extern "C" void kernel_launch(void* const* d_in, const int* in_sizes, int n_in,
                              void* d_out, int out_size, void* d_ws, size_t ws_size,
                              hipStream_t stream) {
    const float* vf   = (const float*)d_in[0];   // [8,128,3,128]
    const float* dist = (const float*)d_in[1];   // [8,128,128,3]
    const float* w    = (const float*)d_in[2];   // [256,128]
    const float* bias = (const float*)d_in[3];   // [128]
    float* out = (float*)d_out;                  // [8,128,128,128]

    const size_t need = (size_t)BB * NN * 3 * 256 * sizeof(float);  // 3 MB
    if (ws_size >= need) {
        float* ac = (float*)d_ws;
        k_pre<<<256, 256, 0, stream>>>(vf, w, ac);
        k_main<<<1024, 256, 0, stream>>>(dist, ac, bias, out);
    } else {
        k_fused_slow<<<BB * NN, 256, 0, stream>>>(vf, dist, w, bias, out);
    }
}

// Round 4
// 27.389 us; speedup vs baseline: 1.8802x; 1.8802x over previous
//
#include <hip/hip_runtime.h>

// B=8, N=128, COOR=3, F=128, FILT=128
#define BB   8
#define NN   128
#define FF   128
#define KK   128

typedef float f32x4 __attribute__((ext_vector_type(4)));

// ---------------------------------------------------------------------------
// Kernel 1: AC[bn][c][k2], k2 in [0,256): k2<128 -> A+bias/2, k2>=128 -> C+bias/2
//   A[bn,c,k] = sum_f vf[bn,c,f] * w[f,k],  C uses w[128+f,k].
// Bias fold: out = sum_c d_c*((A_c+b/2)+(C_c+b/2)) == sum_c d_c*(A+C) + sd*b.
// Grid 512 (2 bn-rows/block, 8 waves/CU). vf rows staged in LDS once; f-loop
// reads are LDS broadcasts; 16 independent w loads in flight per unroll group.
// ---------------------------------------------------------------------------
__global__ __launch_bounds__(256) void k_pre(const float* __restrict__ vf,
                                             const float* __restrict__ w,
                                             const float* __restrict__ bias,
                                             float* __restrict__ ac) {
    const int bn0 = blockIdx.x * 2;
    const int tid = threadIdx.x;
    __shared__ float vfr[768];                     // 2 rows x 3 coor x 128
    if (tid < 192) {
        ((float4*)vfr)[tid] = ((const float4*)(vf + (size_t)bn0 * 384))[tid];
    }
    __syncthreads();

    const int col  = tid & 127;
    const int half = tid >> 7;                     // 0 = A-half, 1 = C-half
    const float* wcol = w + half * (FF * KK) + col;

    float a00 = 0.f, a01 = 0.f, a02 = 0.f;
    float a10 = 0.f, a11 = 0.f, a12 = 0.f;
#pragma unroll 16
    for (int f = 0; f < FF; ++f) {
        const float wv = wcol[f * KK];
        a00 = fmaf(wv, vfr[f],       a00);
        a01 = fmaf(wv, vfr[128 + f], a01);
        a02 = fmaf(wv, vfr[256 + f], a02);
        a10 = fmaf(wv, vfr[384 + f], a10);
        a11 = fmaf(wv, vfr[512 + f], a11);
        a12 = fmaf(wv, vfr[640 + f], a12);
    }
    const float hb = 0.5f * bias[col];
    float* dst = ac + (size_t)bn0 * 768 + half * 128 + col;
    dst[0]    = a00 + hb;  dst[256]  = a01 + hb;  dst[512]  = a02 + hb;
    dst[768]  = a10 + hb;  dst[1024] = a11 + hb;  dst[1280] = a12 + hb;
}

// ---------------------------------------------------------------------------
// Kernel 2: out[b,i,j,k] = sum_c d[b,i,j,c] * (A'[b,i,c,k] + C'[b,j,c,k])
// Grid: 8 * 32(i-tiles of 4) * 4(j-tiles of 32) = 1024 blocks, 256 threads.
// Dist tile (4i x 32j x 3c = 384 floats) staged in LDS once (grid-stride fill
// — 256 threads cover 384 entries!). Per-iter VMEM: 3 C float4 loads + 1
// nontemporal float4 store. A row lives in registers (i constant per thread).
// ---------------------------------------------------------------------------
__global__ __launch_bounds__(256) void k_main(const float* __restrict__ dist,
                                              const float* __restrict__ ac,
                                              float* __restrict__ out) {
    const int bx  = blockIdx.x;
    const int b   = bx >> 7;
    const int rem = bx & 127;
    const int it  = rem >> 2;           // 0..31
    const int jt  = rem & 3;            // 0..3
    const int i0  = it * 4, j0 = jt * 32;
    const int tid = threadIdx.x;

    __shared__ float dl[384];           // [ti][jj][c]
    for (int idx = tid; idx < 384; idx += 256) {
        const int ti = idx / 96, r = idx % 96;
        dl[idx] = dist[((size_t)(b * NN + i0 + ti) * NN + j0) * 3 + r];
    }
    __syncthreads();

    const int k4  = tid & 31;
    const int rg  = tid >> 5;
    const int ti  = rg & 3;
    const int rg4 = rg >> 2;
    const int i   = i0 + ti;

    const float4* arow = (const float4*)(ac + (size_t)(b * NN + i) * 768) + k4;
    const float4 a0 = arow[0], a1 = arow[64], a2 = arow[128];
    float* obase = out + (size_t)(b * NN + i) * NN * KK;
    const float* dlt = dl + ti * 96;

#pragma unroll 4
    for (int p = 0; p < 16; ++p) {
        const int jj = 2 * p + rg4;
        const int j  = j0 + jj;
        const float d0 = dlt[jj * 3], d1 = dlt[jj * 3 + 1], d2 = dlt[jj * 3 + 2];

        const float4* crow = (const float4*)(ac + (size_t)(b * NN + j) * 768)
                             + 32 + k4;          // +128 floats: C-half
        const float4 c0 = crow[0], c1 = crow[64], c2 = crow[128];

        f32x4 r;
        r.x = fmaf(d0, a0.x + c0.x, fmaf(d1, a1.x + c1.x, d2 * (a2.x + c2.x)));
        r.y = fmaf(d0, a0.y + c0.y, fmaf(d1, a1.y + c1.y, d2 * (a2.y + c2.y)));
        r.z = fmaf(d0, a0.z + c0.z, fmaf(d1, a1.z + c1.z, d2 * (a2.z + c2.z)));
        r.w = fmaf(d0, a0.w + c0.w, fmaf(d1, a1.w + c1.w, d2 * (a2.w + c2.w)));

        __builtin_nontemporal_store(r, (f32x4*)(obase + (size_t)j * KK + k4 * 4));
    }
}

// ---------------------------------------------------------------------------
// Fallback (only if ws_size < 3 MB): fused, recomputes C per j. Slow but correct.
// ---------------------------------------------------------------------------
__global__ __launch_bounds__(256) void k_fused_slow(const float* __restrict__ vf,
                                                    const float* __restrict__ dist,
                                                    const float* __restrict__ w,
                                                    const float* __restrict__ bias,
                                                    float* __restrict__ out) {
    const int bi  = blockIdx.x;           // b*NN + i
    const int b   = bi >> 7;
    const int tid = threadIdx.x;
    __shared__ float arow[384];
    __shared__ float crow[384];

    for (int idx = tid; idx < 384; idx += 256) {
        const int c = idx >> 7, k = idx & 127;
        const float* v = vf + (size_t)bi * 384 + c * 128;
        float s = 0.f;
        for (int f = 0; f < 128; ++f) s = fmaf(v[f], w[f * 128 + k], s);
        arow[idx] = s;
    }
    __syncthreads();

    for (int j = 0; j < NN; ++j) {
        for (int idx = tid; idx < 384; idx += 256) {
            const int c = idx >> 7, k = idx & 127;
            const float* v = vf + (size_t)(b * NN + j) * 384 + c * 128;
            float s = 0.f;
            for (int f = 0; f < 128; ++f) s = fmaf(v[f], w[(128 + f) * 128 + k], s);
            crow[idx] = s;
        }
        __syncthreads();
        if (tid < 128) {
            const float* dj = dist + ((size_t)bi * NN + j) * 3;
            const float d0 = dj[0], d1 = dj[1], d2 = dj[2];
            const float sd = d0 + d1 + d2;
            const float r = fmaf(d0, arow[tid] + crow[tid],
                            fmaf(d1, arow[128 + tid] + crow[128 + tid],
                            fmaf(d2, arow[256 + tid] + crow[256 + tid], sd * bias[tid])));
            out[((size_t)bi * NN + j) * 128 + tid] = r;
        }
        __syncthreads();
    }
}

extern "C" void kernel_launch(void* const* d_in, const int* in_sizes, int n_in,
                              void* d_out, int out_size, void* d_ws, size_t ws_size,
                              hipStream_t stream) {
    const float* vf   = (const float*)d_in[0];   // [8,128,3,128]
    const float* dist = (const float*)d_in[1];   // [8,128,128,3]
    const float* w    = (const float*)d_in[2];   // [256,128]
    const float* bias = (const float*)d_in[3];   // [128]
    float* out = (float*)d_out;                  // [8,128,128,128]

    const size_t need = (size_t)BB * NN * 3 * 256 * sizeof(float);  // 3 MB
    if (ws_size >= need) {
        float* ac = (float*)d_ws;
        k_pre<<<512, 256, 0, stream>>>(vf, w, bias, ac);
        k_main<<<1024, 256, 0, stream>>>(dist, ac, out);
    } else {
        k_fused_slow<<<BB * NN, 256, 0, stream>>>(vf, dist, w, bias, out);
    }
}